// Round 13
// baseline (190.422 us; speedup 1.0000x reference)
//
#include <hip/hip_runtime.h>
#include <math.h>

// RWKV block forward, MI355X — round 13: dw1 GEMM merged into the rkvg batched
// launch (per-slot Nz/Kz overrides). 15 dispatches.
#define T_  512
#define E_  1024
#define BTE 1048576

enum { EPI_NONE=0, EPI_TANH=1, EPI_SILU=2, EPI_RELU2=3, EPI_WLOG=4, EPI_ADDRES=5,
       EPI_SIGMUL4=6, EPI_MIX5=7 };

typedef __attribute__((ext_vector_type(8))) short bf16x8;
typedef __attribute__((ext_vector_type(4))) float f32x4;

__device__ __forceinline__ unsigned short f2bf(float f) {
    union { float f; unsigned u; } v; v.f = f;
    unsigned r = v.u + 0x7fffu + ((v.u >> 16) & 1u);
    return (unsigned short)(r >> 16);
}
__device__ __forceinline__ float bf2f(unsigned short h) {
    union { unsigned u; float f; } v; v.u = ((unsigned)h) << 16;
    return v.f;
}

// ---------------- prep: ALL weight transposes + fused LN1+mix in ONE launch ----------------
struct WTA {
    const float* src[16];
    unsigned short* dst[16];
    int K[16], N[16], Npad[16], Kpad[16], tx[16];
    int cum[17];
};
struct PrepArgs {
    WTA wt;
    const float *x, *sc, *bi, *maa;
    float* xn;
    unsigned short* xmix;
    int nwt;
};
__global__ __launch_bounds__(256) void prep_k(PrepArgs p)
{
    const int tid = threadIdx.x;
    if ((int)blockIdx.x < p.nwt) {
        int bid = blockIdx.x;
        int s = 0;
        while (bid >= p.wt.cum[s+1]) ++s;
        const int local = bid - p.wt.cum[s];
        const int bx = local % p.wt.tx[s];
        const int by = local / p.wt.tx[s];
        const float* S = p.wt.src[s];
        unsigned short* D = p.wt.dst[s];
        const int K = p.wt.K[s], N = p.wt.N[s], Npad = p.wt.Npad[s], Kpad = p.wt.Kpad[s];
        __shared__ float t[64][65];
        const int k0 = by*64, n0 = bx*64;
        #pragma unroll
        for (int i = 0; i < 16; ++i) {
            int r = i*4 + (tid >> 6), c = tid & 63;
            int gk = k0 + r, gn = n0 + c;
            t[r][c] = (gk < K && gn < N) ? S[(size_t)gk*N + gn] : 0.f;
        }
        __syncthreads();
        #pragma unroll
        for (int i = 0; i < 16; ++i) {
            int r = i*4 + (tid >> 6), c = tid & 63;
            int gn = n0 + r, gk = k0 + c;
            if (gn < Npad && gk < Kpad)
                D[(size_t)gn*Kpad + gk] = f2bf(t[c][r]);
        }
        return;
    }
    const int row = blockIdx.x - p.nwt;
    const int t = row & 511;
    const float* xr = p.x + (size_t)row * E_;
    float4 v = *reinterpret_cast<const float4*>(xr + tid*4);
    float4 vp = make_float4(0.f, 0.f, 0.f, 0.f);
    if (t) vp = *reinterpret_cast<const float4*>(xr - E_ + tid*4);
    float s   = v.x + v.y + v.z + v.w;
    float ss  = v.x*v.x + v.y*v.y + v.z*v.z + v.w*v.w;
    float sp  = vp.x + vp.y + vp.z + vp.w;
    float ssp = vp.x*vp.x + vp.y*vp.y + vp.z*vp.z + vp.w*vp.w;
    #pragma unroll
    for (int off = 32; off > 0; off >>= 1) {
        s   += __shfl_down(s, off);
        ss  += __shfl_down(ss, off);
        sp  += __shfl_down(sp, off);
        ssp += __shfl_down(ssp, off);
    }
    __shared__ float p0[4], p1[4], p2[4], p3[4];
    __shared__ float st[4];
    if ((tid & 63) == 0) { p0[tid>>6]=s; p1[tid>>6]=ss; p2[tid>>6]=sp; p3[tid>>6]=ssp; }
    __syncthreads();
    if (tid == 0) {
        float S  = p0[0]+p0[1]+p0[2]+p0[3];
        float SS = p1[0]+p1[1]+p1[2]+p1[3];
        float Sp = p2[0]+p2[1]+p2[2]+p2[3];
        float SSp= p3[0]+p3[1]+p3[2]+p3[3];
        float mu  = S * (1.f/E_);
        float var = SS * (1.f/E_) - mu*mu;
        float mup = Sp * (1.f/E_);
        float varp= SSp * (1.f/E_) - mup*mup;
        st[0] = mu; st[1] = rsqrtf(var + 1e-5f);
        st[2] = mup; st[3] = rsqrtf(varp + 1e-5f);
    }
    __syncthreads();
    const float mu = st[0], rstd = st[1], mup = st[2], rstdp = st[3];
    float4 s4 = *reinterpret_cast<const float4*>(p.sc + tid*4);
    float4 b4 = *reinterpret_cast<const float4*>(p.bi + tid*4);
    float xnv[4], prv[4];
    xnv[0]=(v.x-mu)*rstd*s4.x+b4.x; xnv[1]=(v.y-mu)*rstd*s4.y+b4.y;
    xnv[2]=(v.z-mu)*rstd*s4.z+b4.z; xnv[3]=(v.w-mu)*rstd*s4.w+b4.w;
    prv[0]=t?(vp.x-mup)*rstdp*s4.x+b4.x:0.f; prv[1]=t?(vp.y-mup)*rstdp*s4.y+b4.y:0.f;
    prv[2]=t?(vp.z-mup)*rstdp*s4.z+b4.z:0.f; prv[3]=t?(vp.w-mup)*rstdp*s4.w+b4.w:0.f;
    float4 o; o.x=xnv[0]; o.y=xnv[1]; o.z=xnv[2]; o.w=xnv[3];
    *reinterpret_cast<float4*>(p.xn + (size_t)row*E_ + tid*4) = o;
    #pragma unroll
    for (int j = 0; j < 4; ++j) {
        int e = tid*4 + j;
        p.xmix[(size_t)row*E_ + e] = f2bf(xnv[j] + (prv[j]-xnv[j])*p.maa[e]);
    }
}

// ---------------- fused Wo-splitK reduce + residual + LN2 + channel-shift ----------------
__global__ __launch_bounds__(256) void ln2mix_k(const float* __restrict__ pa,
        const float* __restrict__ pb, const float* __restrict__ xres,
        const float* __restrict__ sc, const float* __restrict__ bi,
        const float* __restrict__ maaK, const float* __restrict__ maaR,
        float* __restrict__ x2out,
        unsigned short* __restrict__ ak, unsigned short* __restrict__ ar)
{
    const int row = blockIdx.x;
    const int t = row & 511;
    const int tid = threadIdx.x;
    const size_t off = (size_t)row*E_ + tid*4;
    float4 a0 = *reinterpret_cast<const float4*>(pa + off);
    float4 a1 = *reinterpret_cast<const float4*>(pb + off);
    float4 xv = *reinterpret_cast<const float4*>(xres + off);
    float4 v;
    v.x = a0.x + a1.x + xv.x; v.y = a0.y + a1.y + xv.y;
    v.z = a0.z + a1.z + xv.z; v.w = a0.w + a1.w + xv.w;
    float4 vp = make_float4(0.f, 0.f, 0.f, 0.f);
    if (t) {
        float4 b0 = *reinterpret_cast<const float4*>(pa + off - E_);
        float4 b1 = *reinterpret_cast<const float4*>(pb + off - E_);
        float4 bx = *reinterpret_cast<const float4*>(xres + off - E_);
        vp.x = b0.x + b1.x + bx.x; vp.y = b0.y + b1.y + bx.y;
        vp.z = b0.z + b1.z + bx.z; vp.w = b0.w + b1.w + bx.w;
    }
    *reinterpret_cast<float4*>(x2out + off) = v;
    float s   = v.x + v.y + v.z + v.w;
    float ss  = v.x*v.x + v.y*v.y + v.z*v.z + v.w*v.w;
    float sp  = vp.x + vp.y + vp.z + vp.w;
    float ssp = vp.x*vp.x + vp.y*vp.y + vp.z*vp.z + vp.w*vp.w;
    #pragma unroll
    for (int off2 = 32; off2 > 0; off2 >>= 1) {
        s   += __shfl_down(s, off2);
        ss  += __shfl_down(ss, off2);
        sp  += __shfl_down(sp, off2);
        ssp += __shfl_down(ssp, off2);
    }
    __shared__ float q0[4], q1[4], q2[4], q3[4];
    __shared__ float st[4];
    if ((tid & 63) == 0) { q0[tid>>6]=s; q1[tid>>6]=ss; q2[tid>>6]=sp; q3[tid>>6]=ssp; }
    __syncthreads();
    if (tid == 0) {
        float S  = q0[0]+q0[1]+q0[2]+q0[3];
        float SS = q1[0]+q1[1]+q1[2]+q1[3];
        float Sp = q2[0]+q2[1]+q2[2]+q2[3];
        float SSp= q3[0]+q3[1]+q3[2]+q3[3];
        float mu  = S * (1.f/E_);
        float var = SS * (1.f/E_) - mu*mu;
        float mup = Sp * (1.f/E_);
        float varp= SSp * (1.f/E_) - mup*mup;
        st[0] = mu; st[1] = rsqrtf(var + 1e-5f);
        st[2] = mup; st[3] = rsqrtf(varp + 1e-5f);
    }
    __syncthreads();
    const float mu = st[0], rstd = st[1], mup = st[2], rstdp = st[3];
    float4 s4 = *reinterpret_cast<const float4*>(sc + tid*4);
    float4 b4 = *reinterpret_cast<const float4*>(bi + tid*4);
    float xnv[4], prv[4];
    xnv[0]=(v.x-mu)*rstd*s4.x+b4.x; xnv[1]=(v.y-mu)*rstd*s4.y+b4.y;
    xnv[2]=(v.z-mu)*rstd*s4.z+b4.z; xnv[3]=(v.w-mu)*rstd*s4.w+b4.w;
    prv[0]=t?(vp.x-mup)*rstdp*s4.x+b4.x:0.f; prv[1]=t?(vp.y-mup)*rstdp*s4.y+b4.y:0.f;
    prv[2]=t?(vp.z-mup)*rstdp*s4.z+b4.z:0.f; prv[3]=t?(vp.w-mup)*rstdp*s4.w+b4.w:0.f;
    #pragma unroll
    for (int j = 0; j < 4; ++j) {
        int e = tid*4 + j;
        float sxv = prv[j] - xnv[j];
        ak[(size_t)row*E_ + e] = f2bf(xnv[j] + sxv*maaK[e]);
        ar[(size_t)row*E_ + e] = f2bf(xnv[j] + sxv*maaR[e]);
    }
}

// ---------------- t5 split-K reduce + tanh + repack ----------------
__global__ __launch_bounds__(256) void t5red_k(const float* __restrict__ tp,
        unsigned short* __restrict__ t5p)
{
    int idx = blockIdx.x*256 + threadIdx.x;          // < 5*1024*64
    int c = idx & 63, bt = (idx >> 6) & 1023, g = idx >> 16;
    unsigned short o = 0;
    if (c < 32) {
        float s = 0.f;
        size_t off = (size_t)bt*160 + g*32 + c;
        #pragma unroll
        for (int z = 0; z < 8; ++z) s += tp[(size_t)z*163840 + off];
        o = f2bf(tanhf(s));
    }
    t5p[idx] = o;
}

// ---------------- dw1 split-K reduce + tanh -> bf16 ----------------
__global__ __launch_bounds__(256) void dw1red_k(const float* __restrict__ dp,
        unsigned short* __restrict__ h)
{
    int idx = blockIdx.x*256 + threadIdx.x;          // < 65536
    float s = 0.f;
    #pragma unroll
    for (int z = 0; z < 8; ++z) s += dp[(size_t)z*65536 + idx];
    h[idx] = f2bf(tanhf(s));
}

// ---------------- 64x64-tile bf16 MFMA GEMM (split-K + XCD swizzle, per-slot N/K) ----------------
struct GemmArgs {
    const unsigned short* A[12];
    const unsigned short* B[12];
    void* C[12];
    const float* p1[12];
    const float* p2[12];
    int epi[12];
    int obf[12];
    int k0[12];
    int Nz[12];          // 0 -> g.N
    int Kz[12];          // 0 -> g.K
    int M, N, K, ldK;
    // EPI_MIX5 extras
    const float* xnp;
    const float* maa5[5];
    unsigned short* dst5[5];
};
__global__ __launch_bounds__(256) void mgemm_k(GemmArgs g)
{
    const int bz = blockIdx.z;
    const unsigned short* Ag = g.A[bz];
    const unsigned short* BT = g.B[bz];
    const int Nact = g.Nz[bz] ? g.Nz[bz] : g.N;
    const int Kact = g.Kz[bz] ? g.Kz[bz] : g.K;
    const int gx = gridDim.x, gy = gridDim.y;
    const int lin = blockIdx.x + gx*blockIdx.y;
    const int q = (gx*gy) >> 3;
    const int tile = (lin & 7)*q + (lin >> 3);
    const int bx = tile / gy;
    const int by = tile - bx*gy;
    const int m0 = by * 64, n0 = bx * 64;
    if (n0 >= Nact) return;
    const int tid = threadIdx.x;
    const int lane = tid & 63, w = tid >> 6;

    __shared__ __align__(16) unsigned short As[2][4096];
    __shared__ __align__(16) unsigned short Bs[2][4096];

    const size_t rowBytes = (size_t)g.ldK * 2;
    int sI[4], sIsB[4]; size_t sOff[4];
    #pragma unroll
    for (int ii = 0; ii < 4; ++ii) {
        int t = w*4 + ii;
        int isB = t >> 3;
        int i = t & 7;
        int r = i*8 + (lane >> 3);
        int gb = ((lane & 7) * 16) ^ ((r & 7) << 4);
        sI[ii] = i; sIsB[ii] = isB;
        int srow = (isB ? n0 : m0) + r;
        sOff[ii] = (size_t)srow * rowBytes + gb;
    }
    auto stage = [&](int buf, size_t kbyte) {
        #pragma unroll
        for (int ii = 0; ii < 4; ++ii) {
            const char* src = (const char*)(sIsB[ii] ? BT : Ag) + sOff[ii] + kbyte;
            unsigned short* dst = (sIsB[ii] ? Bs[buf] : As[buf]) + sI[ii]*512;
            auto g1 = (const __attribute__((address_space(1))) unsigned int*)(src);
            auto l3 = (__attribute__((address_space(3))) unsigned int*)(uintptr_t)(dst);
            __builtin_amdgcn_global_load_lds(g1, l3, 16, 0, 0);
        }
    };

    const int wm = (w >> 1) * 32, wn = (w & 1) * 32;
    const int lr = lane & 15, lk = lane >> 4;
    int aoff[2][2], boff[2][2];
    #pragma unroll
    for (int mi = 0; mi < 2; ++mi)
        #pragma unroll
        for (int kw = 0; kw < 2; ++kw) {
            int ar = wm + mi*16 + lr;
            aoff[mi][kw] = ar*128 + ((kw*64 + lk*16) ^ ((ar & 7) << 4));
            int br = wn + mi*16 + lr;
            boff[mi][kw] = br*128 + ((kw*64 + lk*16) ^ ((br & 7) << 4));
        }

    f32x4 acc[2][2] = {};
    const size_t kbase = (size_t)g.k0[bz] * 2;
    stage(0, kbase);
    const int nk = Kact >> 6;
    int cur = 0;
    for (int kt = 0; kt < nk; ++kt) {
        __syncthreads();
        if (kt + 1 < nk) stage(cur ^ 1, kbase + (size_t)(kt + 1) * 128);
        const char* Ab = (const char*)As[cur];
        const char* Bb = (const char*)Bs[cur];
        bf16x8 af[2][2], bfv[2][2];
        #pragma unroll
        for (int mi = 0; mi < 2; ++mi)
            #pragma unroll
            for (int kw = 0; kw < 2; ++kw) {
                af[mi][kw]  = *(const bf16x8*)(Ab + aoff[mi][kw]);
                bfv[mi][kw] = *(const bf16x8*)(Bb + boff[mi][kw]);
            }
        #pragma unroll
        for (int kw = 0; kw < 2; ++kw)
            #pragma unroll
            for (int mi = 0; mi < 2; ++mi)
                #pragma unroll
                for (int ni = 0; ni < 2; ++ni)
                    acc[mi][ni] = __builtin_amdgcn_mfma_f32_16x16x32_bf16(
                        af[mi][kw], bfv[ni][kw], acc[mi][ni], 0, 0, 0);
        cur ^= 1;
    }

    const int epi = g.epi[bz], obf = g.obf[bz];
    const float* p1 = g.p1[bz];
    const float* p2 = g.p2[bz];
    float* Cf = (float*)g.C[bz];
    unsigned short* Ch = (unsigned short*)g.C[bz];
    #pragma unroll
    for (int mi = 0; mi < 2; ++mi) {
        #pragma unroll
        for (int ni = 0; ni < 2; ++ni) {
            #pragma unroll
            for (int j = 0; j < 4; ++j) {
                int gm = m0 + wm + mi*16 + lk*4 + j;
                int gn = n0 + wn + ni*16 + lr;
                if (gn >= Nact) continue;
                size_t idx = (size_t)gm * Nact + gn;
                float a = acc[mi][ni][j];
                if (epi == EPI_MIX5) {
                    int bs = gm >> 9, t = gm & 511;
                    int L = bs*5 + bz;
                    int o5 = L >> 1, bd = L & 1;
                    size_t drow = (size_t)(bd*T_ + t)*E_ + gn;
                    float xnv = g.xnp[drow];
                    float prev = t ? g.xnp[drow - E_] : 0.f;
                    g.dst5[o5][drow] = f2bf(xnv + (prev - xnv)*(g.maa5[o5][gn] + a));
                    continue;
                }
                float o = a;
                if (epi == EPI_TANH)        o = tanhf(a);
                else if (epi == EPI_SILU)   o = a / (1.f + expf(-a));
                else if (epi == EPI_RELU2)  { float r = fmaxf(a, 0.f); o = r*r; }
                else if (epi == EPI_WLOG) {
                    float z = -(p1[gn] + a);
                    float sp = (z > 15.f) ? z : log1pf(expf(z));
                    o = logf(fminf(fmaxf(sp, 1e-6f), 1.f));
                }
                else if (epi == EPI_ADDRES) o = a + p1[idx];
                else if (epi == EPI_SIGMUL4) {
                    float kvs = p1[idx] + p1[idx + BTE] + p1[idx + 2*BTE] + p1[idx + 3*BTE];
                    o = p2[idx] + kvs / (1.f + expf(-a));
                }
                if (obf) Ch[idx] = f2bf(o); else Cf[idx] = o;
            }
        }
    }
}

// ---------------- chunkwise pass 1: 1024 threads, early r/k/v prefetch ----------------
#define SWZI(r, c)  (((r) << 6) + ((c) ^ (((r) & 7) << 3)))
#define FIDX(r, kw) (((r) << 6) + ((((kw)*32) + fk*8) ^ (((r) & 7) << 3)))
__global__ __launch_bounds__(1024, 4) void chunk1_k(
    const unsigned short* __restrict__ rb, const unsigned short* __restrict__ kb,
    const unsigned short* __restrict__ vb,
    const unsigned short* __restrict__ hdecb, const unsigned short* __restrict__ dw2T,
    const float* __restrict__ tdecay, const float* __restrict__ faaaa,
    float* __restrict__ ypart, unsigned short* __restrict__ Ug,
    unsigned short* __restrict__ RDimg, unsigned short* __restrict__ BFb,
    float* __restrict__ B63g)
{
    const int blk = blockIdx.x;           // bh*8 + nc
    const int bh = blk >> 3, nc = blk & 7;
    const int b = bh >> 4, h = bh & 15;
    const int tid = threadIdx.x;
    const int l = tid & 63, w = tid >> 6;          // w in [0,16)
    const int jl = l, q = w;
    const int fr = l & 15, fk = l >> 4;
    const int wm = (w >> 2) * 16, wn = (w & 3) * 16;
    const int t0 = nc * 64;

    __shared__ float sQS[16][64];
    __shared__ float sUD[64];
    __shared__ __align__(16) unsigned short pool[32768];   // 64 KB
    unsigned short* sRDb  = pool;
    unsigned short* sKAb  = pool + 4096;
    unsigned short* sKA2b = pool + 8192;
    unsigned short* sKATb = pool + 12288;
    unsigned short* sVTb  = pool + 16384;
    unsigned short* sVXTb = pool + 20480;
    unsigned short* sQMb  = pool + 24576;
    unsigned short* sPMb  = pool + 28672;
    float* wlogf = (float*)(pool + 12288);

    const float u_reg = faaaa[h*64 + jl];
    const size_t base = (size_t)b*T_*E_ + (size_t)h*64;
    const size_t coff = (size_t)blk * 4096;

    unsigned short rh[4], kh[4], vh[4];
    #pragma unroll
    for (int c = 0; c < 4; ++c) {
        const size_t gi = base + (size_t)(t0 + q*4 + c)*E_ + jl;
        rh[c] = rb[gi]; kh[c] = kb[gi]; vh[c] = vb[gi];
    }

    {
        const int isB = w >> 3;
        const int i = w & 7;
        const int r = i*8 + (l >> 3);
        const int gb = ((l & 7)*16) ^ ((r & 7) << 4);
        const char* src = isB
            ? ((const char*)dw2T  + (size_t)(h*64 + r)*128 + gb)
            : ((const char*)hdecb + (size_t)(b*T_ + t0 + r)*128 + gb);
        unsigned short* dst = (isB ? sPMb : sQMb) + i*512;
        auto g1 = (const __attribute__((address_space(1))) unsigned int*)(src);
        auto l3 = (__attribute__((address_space(3))) unsigned int*)(uintptr_t)(dst);
        __builtin_amdgcn_global_load_lds(g1, l3, 16, 0, 0);
    }
    __syncthreads();

    {
        f32x4 accO = {};
        #pragma unroll
        for (int kw = 0; kw < 2; ++kw) {
            bf16x8 aH = *(const bf16x8*)(&sQMb[FIDX(wm + fr, kw)]);
            bf16x8 bD = *(const bf16x8*)(&sPMb[FIDX(wn + fr, kw)]);
            accO = __builtin_amdgcn_mfma_f32_16x16x32_bf16(aH, bD, accO, 0,0,0);
        }
        const float td = tdecay[h*64 + wn + fr];
        #pragma unroll
        for (int reg = 0; reg < 4; ++reg) {
            const int t = wm + fk*4 + reg;
            const int col = wn + fr;
            float z = -(td + accO[reg]);
            float sp = (z > 15.f) ? z : log1pf(expf(z));
            wlogf[t*64 + col] = logf(fminf(fmaxf(sp, 1e-6f), 1.f));
        }
    }
    __syncthreads();

    float loc[4], vreg[4];
    {
        float cum = 0.f;
        #pragma unroll
        for (int c = 0; c < 4; ++c) {
            float wv = wlogf[(q*4 + c)*64 + jl];
            cum += wv; loc[c] = cum;
        }
        sQS[q][jl] = cum;
    }
    __syncthreads();
    float pre = 0.f, atot = 0.f;
    #pragma unroll
    for (int qq = 0; qq < 16; ++qq) {
        float v = sQS[qq][jl];
        atot += v;
        if (qq < q) pre += v;
    }

    #pragma unroll
    for (int c = 0; c < 4; ++c) {
        const int t = q*4 + c;
        const float rv = bf2f(rh[c]), kv = bf2f(kh[c]), vv = bf2f(vh[c]);
        vreg[c] = vv;
        const float a = loc[c] + pre;
        const float aprev = (c > 0) ? (loc[c-1] + pre) : pre;
        sRDb [SWZI(t, jl)] = f2bf(rv * expf(aprev));
        const float ka = kv * expf(atot - a);
        sKAb [SWZI(t, jl)] = f2bf(ka);
        sKA2b[SWZI(t, jl)] = f2bf(kv * expf(-a));
        sKATb[SWZI(jl, t)] = f2bf(ka);
        sVTb [SWZI(jl, t)] = f2bf(vv);
        float p = rv * u_reg * kv;
        #pragma unroll
        for (int off = 32; off > 0; off >>= 1) p += __shfl_down(p, off);
        if (jl == 0) sUD[t] = p;
    }
    __syncthreads();

    f32x4 accQ = {}, accP = {};
    #pragma unroll
    for (int kw = 0; kw < 2; ++kw) {
        bf16x8 ar  = *(const bf16x8*)(&sRDb [FIDX(wm + fr, kw)]);
        bf16x8 bka = *(const bf16x8*)(&sKAb [FIDX(wn + fr, kw)]);
        bf16x8 bk2 = *(const bf16x8*)(&sKA2b[FIDX(wn + fr, kw)]);
        accQ = __builtin_amdgcn_mfma_f32_16x16x32_bf16(ar, bk2, accQ, 0,0,0);
        accP = __builtin_amdgcn_mfma_f32_16x16x32_bf16(ar, bka, accP, 0,0,0);
    }
    #pragma unroll
    for (int reg = 0; reg < 4; ++reg) {
        int t = wm + fk*4 + reg;
        int s = wn + fr;
        float qv = (s < t) ? accQ[reg] : ((s == t) ? sUD[t] : 0.f);
        float pv = (s < t) ? accP[reg] : 0.f;
        sQMb[SWZI(t, s)] = f2bf(qv);
        sPMb[SWZI(t, s)] = f2bf(pv);
    }

    float loc2[4];
    {
        float cum2 = 0.f;
        #pragma unroll
        for (int c = 0; c < 4; ++c) {
            cum2 += loc[c] + pre;
            loc2[c] = cum2;
        }
        sQS[q][jl] = cum2;
    }
    __syncthreads();
    {
        float pre2 = 0.f;
        #pragma unroll
        for (int qq = 0; qq < 16; ++qq) if (qq < q) pre2 += sQS[qq][jl];
        #pragma unroll
        for (int c = 0; c < 4; ++c) {
            const int t = q*4 + c;
            const float Bv = loc2[c] + pre2;
            const float Bprev = (c > 0) ? (loc2[c-1] + pre2) : pre2;
            const unsigned short bfh = f2bf(expf(Bprev));
            sKA2b[t*64 + jl] = bfh;
            BFb[coff + t*64 + jl] = bfh;
            sVXTb[SWZI(jl, t)] = f2bf(vreg[c] * expf(-Bv));
            if (t == 63) B63g[(size_t)blk*64 + jl] = expf(Bv);
        }
    }
    __syncthreads();

    {
        f32x4 accI = {}, accL = {}, accU = {};
        #pragma unroll
        for (int kw = 0; kw < 2; ++kw) {
            bf16x8 aQ = *(const bf16x8*)(&sQMb [FIDX(wm + fr, kw)]);
            bf16x8 aP = *(const bf16x8*)(&sPMb [FIDX(wm + fr, kw)]);
            bf16x8 aK = *(const bf16x8*)(&sKATb[FIDX(wm + fr, kw)]);
            bf16x8 bV = *(const bf16x8*)(&sVTb [FIDX(wn + fr, kw)]);
            bf16x8 bX = *(const bf16x8*)(&sVXTb[FIDX(wn + fr, kw)]);
            accI = __builtin_amdgcn_mfma_f32_16x16x32_bf16(aQ, bV, accI, 0,0,0);
            accL = __builtin_amdgcn_mfma_f32_16x16x32_bf16(aP, bX, accL, 0,0,0);
            accU = __builtin_amdgcn_mfma_f32_16x16x32_bf16(aK, bX, accU, 0,0,0);
        }
        #pragma unroll
        for (int reg = 0; reg < 4; ++reg) {
            int t = wm + fk*4 + reg;
            int k = wn + fr;
            float bfv = bf2f(sKA2b[t*64 + k]);
            ypart[base + (size_t)(t0 + t)*E_ + k] = accI[reg] + bfv*accL[reg];
            Ug[coff + t*64 + k] = f2bf(accU[reg]);
        }
    }
    if (tid < 512)
        ((bf16x8*)(RDimg + coff))[tid] = ((const bf16x8*)sRDb)[tid];
}

// ---------------- chunkwise pass 2: sequential state scan (Ug bf16) ----------------
__global__ __launch_bounds__(256) void chunk2_k(
    const float* __restrict__ st_in, const unsigned short* __restrict__ Ug,
    const float* __restrict__ B63g,
    unsigned short* __restrict__ Simg, float* __restrict__ st_out)
{
    const int bh = blockIdx.x;
    const int tid = threadIdx.x;
    __shared__ float S[4096];
    for (int i = tid; i < 4096; i += 256) S[i] = st_in[(size_t)bh*4096 + i];
    __syncthreads();
    const int k = tid >> 2, j0 = (tid & 3) * 16;
    for (int nc = 0; nc < 8; ++nc) {
        const size_t coff = ((size_t)bh*8 + nc) * 4096;
        #pragma unroll
        for (int hf = 0; hf < 2; ++hf) {
            bf16x8 tmp;
            #pragma unroll
            for (int e = 0; e < 8; ++e) tmp[e] = (short)f2bf(S[(j0 + hf*8 + e)*64 + k]);
            *(bf16x8*)(&Simg[coff + SWZI(k, j0 + hf*8)]) = tmp;
        }
        __syncthreads();
        for (int i = tid; i < 4096; i += 256) {
            int kk = i & 63;
            S[i] = B63g[((size_t)bh*8 + nc)*64 + kk] * (S[i] + bf2f(Ug[coff + i]));
        }
        __syncthreads();
    }
    for (int i = tid; i < 4096; i += 256) st_out[(size_t)bh*4096 + i] = S[i];
}

// ---------------- chunkwise pass 3: y += BF*(RD@S_prev) + GN partials ----------------
__global__ __launch_bounds__(256) void chunk3_k(
    const unsigned short* __restrict__ RDimg, const unsigned short* __restrict__ Simg,
    const unsigned short* __restrict__ BFb, float* __restrict__ yb,
    float* __restrict__ part)
{
    const int blk = blockIdx.x;
    const int bh = blk >> 3, nc = blk & 7;
    const int b = bh >> 4, h = bh & 15;
    const int tid = threadIdx.x;
    const int l = tid & 63, w = tid >> 6;
    const int fr = l & 15, fk = l >> 4;
    const int wm = (w >> 1) * 32, wn = (w & 1) * 32;
    const int t0 = nc * 64;
    __shared__ __align__(16) unsigned short sRDb[4096];
    __shared__ __align__(16) unsigned short sSTb[4096];
    const size_t coff = (size_t)blk * 4096;

    #pragma unroll
    for (int ii = 0; ii < 2; ++ii) {
        int seg = (w*2 + ii) * 512;
        {
            auto g1 = (const __attribute__((address_space(1))) unsigned int*)(RDimg + coff + seg + (l << 3));
            auto l3 = (__attribute__((address_space(3))) unsigned int*)(uintptr_t)(sRDb + seg);
            __builtin_amdgcn_global_load_lds(g1, l3, 16, 0, 0);
        }
        {
            auto g1 = (const __attribute__((address_space(1))) unsigned int*)(Simg + coff + seg + (l << 3));
            auto l3 = (__attribute__((address_space(3))) unsigned int*)(uintptr_t)(sSTb + seg);
            __builtin_amdgcn_global_load_lds(g1, l3, 16, 0, 0);
        }
    }
    __syncthreads();

    f32x4 accS[2][2] = {};
    #pragma unroll
    for (int kw = 0; kw < 2; ++kw) {
        bf16x8 aR[2], bS[2];
        #pragma unroll
        for (int mi = 0; mi < 2; ++mi)
            aR[mi] = *(const bf16x8*)(&sRDb[FIDX(wm + mi*16 + fr, kw)]);
        #pragma unroll
        for (int ni = 0; ni < 2; ++ni)
            bS[ni] = *(const bf16x8*)(&sSTb[FIDX(wn + ni*16 + fr, kw)]);
        #pragma unroll
        for (int mi = 0; mi < 2; ++mi)
            #pragma unroll
            for (int ni = 0; ni < 2; ++ni)
                accS[mi][ni] = __builtin_amdgcn_mfma_f32_16x16x32_bf16(aR[mi], bS[ni], accS[mi][ni], 0,0,0);
    }
    const size_t base = (size_t)b*T_*E_ + (size_t)h*64;
    float s = 0.f, ss = 0.f;
    #pragma unroll
    for (int mi = 0; mi < 2; ++mi)
        #pragma unroll
        for (int ni = 0; ni < 2; ++ni)
            #pragma unroll
            for (int reg = 0; reg < 4; ++reg) {
                int t = wm + mi*16 + fk*4 + reg;
                int k = wn + ni*16 + fr;
                size_t gp = base + (size_t)(t0 + t)*E_ + k;
                float yv = yb[gp] + bf2f(BFb[coff + t*64 + k]) * accS[mi][ni][reg];
                yb[gp] = yv;
                s += yv; ss += yv*yv;
            }
    #pragma unroll
    for (int off = 32; off > 0; off >>= 1) {
        s  += __shfl_down(s, off);
        ss += __shfl_down(ss, off);
    }
    __shared__ float ps[4], pss[4];
    if (l == 0) { ps[w] = s; pss[w] = ss; }
    __syncthreads();
    if (tid == 0) {
        part[blk]       = ps[0]+ps[1]+ps[2]+ps[3];
        part[256 + blk] = pss[0]+pss[1]+pss[2]+pss[3];
    }
}

// ---------------- gn_apply with per-head reduction from chunk3 partials ----------------
__global__ __launch_bounds__(256) void gn_apply_k(const float* __restrict__ y,
        const float* __restrict__ g, const float* __restrict__ part,
        const float* __restrict__ sc, const float* __restrict__ bi,
        unsigned short* __restrict__ z)
{
    __shared__ float smu[16], srs[16];
    const int tid = threadIdx.x;
    if (tid < 16) {
        float s = 0.f, ss = 0.f;
        #pragma unroll
        for (int b = 0; b < 2; ++b)
            #pragma unroll
            for (int ncc = 0; ncc < 8; ++ncc) {
                int ib = (b*16 + tid)*8 + ncc;
                s  += part[ib];
                ss += part[256 + ib];
            }
        float mu  = s * (1.f/65536.f);
        float var = ss * (1.f/65536.f) - mu*mu;
        smu[tid] = mu;
        srs[tid] = rsqrtf(var + 1e-5f);
    }
    __syncthreads();
    int idx = blockIdx.x*256 + tid;
    int d = idx & 1023;
    int h = d >> 6;
    float yn = (y[idx] - smu[h])*srs[h]*sc[d] + bi[d];
    z[idx] = f2bf(yn * g[idx]);
}

// ---------------- launch ----------------
extern "C" void kernel_launch(void* const* d_in, const int* in_sizes, int n_in,
                              void* d_out, int out_size, void* d_ws, size_t ws_size,
                              hipStream_t stream)
{
    const float* x       = (const float*)d_in[0];
    const float* state0  = (const float*)d_in[1];
    const float* maa_x   = (const float*)d_in[2];
    const float* maa_w   = (const float*)d_in[3];
    const float* maa_k   = (const float*)d_in[4];
    const float* maa_v   = (const float*)d_in[5];
    const float* maa_r   = (const float*)d_in[6];
    const float* maa_g   = (const float*)d_in[7];
    const float* tdecay  = (const float*)d_in[8];
    const float* faaaa   = (const float*)d_in[9];
    const float* w1      = (const float*)d_in[10];
    const float* w2      = (const float*)d_in[11];
    const float* dw1     = (const float*)d_in[12];
    const float* dw2     = (const float*)d_in[13];
    const float* Wr      = (const float*)d_in[14];
    const float* Wk      = (const float*)d_in[15];
    const float* Wv      = (const float*)d_in[16];
    const float* Wg      = (const float*)d_in[17];
    const float* Wo      = (const float*)d_in[18];
    const float* lnx_s   = (const float*)d_in[19];
    const float* lnx_b   = (const float*)d_in[20];
    const float* maa_kch = (const float*)d_in[21];
    const float* maa_rch = (const float*)d_in[22];
    const float* Wk_ch   = (const float*)d_in[23];
    const float* Wv_ch   = (const float*)d_in[24];
    const float* Wr_ch   = (const float*)d_in[25];
    const float* ln1_s   = (const float*)d_in[26];
    const float* ln1_b   = (const float*)d_in[27];
    const float* ln2_s   = (const float*)d_in[28];
    const float* ln2_b   = (const float*)d_in[29];

    // ---- workspace layout (f32 block) ----
    float* xn     = (float*)d_ws;               // 1M
    float* t5dead = xn + 1048576;               // 163840
    float* gbuf   = t5dead + 163840;            // 1M (t5/kv partial base)
    float* wlogb  = gbuf + 1048576;             // 1M (Wo p0; kv p1)
    float* ybuf   = wlogb + 1048576;            // 1M (Wo p1; kv p2)
    float* kvb    = ybuf + 1048576;             // 1M (kv p3)
    float* gnpart = kvb + 1048576;              // 1024
    float* gnstat = gnpart + 1024;              // 32 (unused)
    float* b63g   = gnstat + 32;                // 16384
    // ---- ushort block ----
    unsigned short* u = (unsigned short*)(b63g + 16384);
    unsigned short* xmix = u;  u += 1048576;    // reused: dw1 partials, BFb, zbuf
    unsigned short* xw   = u;  u += 1048576;    // reused as ak
    unsigned short* xk   = u;  u += 1048576;    // reused as ar
    unsigned short* xv_  = u;  u += 1048576;    // reused: Ug (bf16) / kk[0:1M]
    unsigned short* xr   = u;  u += 1048576;    // kk[1M:2M]
    unsigned short* xg   = u;  u += 1048576;    // reused: RDimg / kk[2M:3M]
    unsigned short* xtr  = u;  u += 1048576;    // reused: Simg  / kk[3M:4M]
    unsigned short* rb   = u;  u += 1048576;
    unsigned short* kb   = u;  u += 1048576;
    unsigned short* vb   = u;  u += 1048576;
    unsigned short* hdecb= u;  u += 65536;
    unsigned short* WrT  = u;  u += 1048576;
    unsigned short* WkT  = u;  u += 1048576;
    unsigned short* WvT  = u;  u += 1048576;
    unsigned short* WgT  = u;  u += 1048576;
    unsigned short* WoT  = u;  u += 1048576;
    unsigned short* WrchT= u;  u += 1048576;
    unsigned short* WkchT= u;  u += 4194304;    // 4096 x 1024
    unsigned short* WvchT= u;  u += 4194304;    // 1024 x 4096
    unsigned short* w1T  = u;  u += 196608;     // 192 x 1024
    unsigned short* dw1T = u;  u += 65536;      // 64 x 1024
    unsigned short* dw2T = u;  u += 65536;      // 1024 x 64
    unsigned short* W2T5 = u;  u += 327680;     // 5 x 1024 x 64
    unsigned short* t5p  = u;  u += 327680;     // 5 x 1024 x 64
    // aliases
    unsigned short* zbuf  = xmix;
    unsigned short* akb   = xw;
    unsigned short* arb   = xk;
    unsigned short* kkb   = xv_;                // 4M ushorts contiguous
    unsigned short* Ug    = xv_;                // 1M ushorts (bf16)
    unsigned short* RDimg = xg;
    unsigned short* Simg  = xtr;
    unsigned short* BFb   = xmix;
    float* tpart = gbuf;        // 8 x 1024x160 f32
    float* dpart = (float*)xmix;// 8 x 1024x64 f32 = 2 MB
    float* kpart = gbuf;        // kv split-K partials: gbuf..kvb contiguous 4xBTE
    float* wop0  = wlogb;       // Wo split-K partials
    float* wop1  = ybuf;

    float* out   = (float*)d_out;
    float* x2buf = out;
    float* stout = out + (size_t)BTE;

    // ---- prep: all weight transposes + LN1+mix in one launch ----
    {
        PrepArgs p{};
        const float* srcs[16] = {Wr, Wk, Wv, Wg, Wo, Wr_ch, Wk_ch, Wv_ch, w1, dw1, dw2,
                                 w2, w2+32768, w2+65536, w2+98304, w2+131072};
        unsigned short* dsts[16] = {WrT, WkT, WvT, WgT, WoT, WrchT, WkchT, WvchT,
                                    w1T, dw1T, dw2T,
                                    W2T5, W2T5+65536, W2T5+131072, W2T5+196608, W2T5+262144};
        int Ks[16]    = {1024,1024,1024,1024,1024,1024, 1024, 4096, 1024, 1024,   64, 32,32,32,32,32};
        int Ns[16]    = {1024,1024,1024,1024,1024,1024, 4096, 1024,  160,   64, 1024, 1024,1024,1024,1024,1024};
        int Npads[16] = {1024,1024,1024,1024,1024,1024, 4096, 1024,  192,   64, 1024, 1024,1024,1024,1024,1024};
        int Kpads[16] = {1024,1024,1024,1024,1024,1024, 1024, 4096, 1024, 1024,   64, 64,64,64,64,64};
        int cum = 0;
        for (int i = 0; i < 16; ++i) {
            p.wt.src[i] = srcs[i]; p.wt.dst[i] = dsts[i];
            p.wt.K[i] = Ks[i]; p.wt.N[i] = Ns[i]; p.wt.Npad[i] = Npads[i]; p.wt.Kpad[i] = Kpads[i];
            int txc = (Ns[i] + 63) / 64;
            int tyc = (Ks[i] + 63) / 64;
            p.wt.tx[i] = txc;
            p.wt.cum[i] = cum;
            cum += txc * tyc;
        }
        p.wt.cum[16] = cum;
        p.nwt = cum;
        p.x = x; p.sc = ln1_s; p.bi = ln1_b; p.maa = maa_x;
        p.xn = xn; p.xmix = xmix;
        prep_k<<<cum + 1024, 256, 0, stream>>>(p);
    }

    // ---- time mixing ----
    // t5 GEMM: split-K x8, single launch
    { GemmArgs g{}; g.M=1024; g.N=160; g.K=128; g.ldK=1024;
      for (int z = 0; z < 8; ++z) {
          g.A[z]=xmix; g.B[z]=w1T; g.C[z]=tpart + (size_t)z*163840;
          g.epi[z]=EPI_NONE; g.obf[z]=0; g.k0[z]=z*128;
      }
      mgemm_k<<<dim3(3,16,8), 256, 0, stream>>>(g); }
    t5red_k<<<1280, 256, 0, stream>>>(tpart, t5p);
    // m GEMM with fused mix5 epilogue -> writes xw/xk/xv/xr/xg directly
    { GemmArgs g{}; g.M=1024; g.N=1024; g.K=64; g.ldK=64;
      g.xnp = xn;
      g.maa5[0]=maa_w; g.maa5[1]=maa_k; g.maa5[2]=maa_v; g.maa5[3]=maa_r; g.maa5[4]=maa_g;
      g.dst5[0]=xw; g.dst5[1]=xk; g.dst5[2]=xv_; g.dst5[3]=xr; g.dst5[4]=xg;
      for (int z = 0; z < 5; ++z) {
          g.A[z]=t5p + (size_t)z*65536; g.B[z]=W2T5 + (size_t)z*65536;
          g.C[z]=nullptr; g.epi[z]=EPI_MIX5; g.obf[z]=0;
      }
      mgemm_k<<<dim3(16,16,5), 256, 0, stream>>>(g); }
    // rkvg GEMM batch + dw1 split-K x8 merged into one launch (12 z-slices)
    { GemmArgs g{}; g.M=1024; g.N=1024; g.K=1024; g.ldK=1024;
      g.A[0]=xr;  g.B[0]=WrT; g.C[0]=rb;   g.epi[0]=EPI_NONE; g.obf[0]=1;
      g.A[1]=xk;  g.B[1]=WkT; g.C[1]=kb;   g.epi[1]=EPI_NONE; g.obf[1]=1;
      g.A[2]=xv_; g.B[2]=WvT; g.C[2]=vb;   g.epi[2]=EPI_NONE; g.obf[2]=1;
      g.A[3]=xg;  g.B[3]=WgT; g.C[3]=gbuf; g.epi[3]=EPI_SILU; g.obf[3]=0;
      for (int z = 0; z < 8; ++z) {
          g.A[4+z]=xw; g.B[4+z]=dw1T; g.C[4+z]=dpart + (size_t)z*65536;
          g.epi[4+z]=EPI_NONE; g.obf[4+z]=0; g.k0[4+z]=z*128;
          g.Nz[4+z]=64; g.Kz[4+z]=128;
      }
      mgemm_k<<<dim3(16,16,12), 256, 0, stream>>>(g); }
    dw1red_k<<<256, 256, 0, stream>>>(dpart, hdecb);

    // chunkwise: pass1 (prefetch + 16 waves) -> tiny scan -> pass2 (+GN partials)
    chunk1_k<<<256, 1024, 0, stream>>>(rb, kb, vb, hdecb, dw2T, tdecay, faaaa,
                                       ybuf, Ug, RDimg, BFb, b63g);
    chunk2_k<<<32, 256, 0, stream>>>(state0, Ug, b63g, Simg, stout);
    chunk3_k<<<256, 256, 0, stream>>>(RDimg, Simg, BFb, ybuf, gnpart);

    gn_apply_k<<<4096, 256, 0, stream>>>(ybuf, gbuf, gnpart, lnx_s, lnx_b, zbuf);
    // Wo GEMM: split-K x2 into f32 partials (reduce folded into ln2mix)
    { GemmArgs g{}; g.M=1024; g.N=1024; g.K=512; g.ldK=1024;
      g.A[0]=zbuf; g.B[0]=WoT; g.C[0]=wop0; g.epi[0]=EPI_NONE; g.obf[0]=0; g.k0[0]=0;
      g.A[1]=zbuf; g.B[1]=WoT; g.C[1]=wop1; g.epi[1]=EPI_NONE; g.obf[1]=0; g.k0[1]=512;
      mgemm_k<<<dim3(16,16,2), 256, 0, stream>>>(g); }

    // ---- channel mixing (x2 = wop0 + wop1 + x computed inline) ----
    ln2mix_k<<<1024, 256, 0, stream>>>(wop0, wop1, x, ln2_s, ln2_b,
                                       maa_kch, maa_rch, x2buf, akb, arb);
    { GemmArgs g{}; g.M=1024; g.N=4096; g.K=1024; g.ldK=1024;
      g.A[0]=akb; g.B[0]=WkchT; g.C[0]=kkb; g.epi[0]=EPI_RELU2; g.obf[0]=1;
      mgemm_k<<<dim3(64,16,1), 256, 0, stream>>>(g); }
    { GemmArgs g{}; g.M=1024; g.N=1024; g.K=1024; g.ldK=4096;   // split-K over K=4096
      for (int z = 0; z < 4; ++z) {
          g.A[z]=kkb; g.B[z]=WvchT; g.C[z]=kpart + (size_t)z*BTE;
          g.epi[z]=EPI_NONE; g.obf[z]=0; g.k0[z]=z*1024;
      }
      mgemm_k<<<dim3(16,16,4), 256, 0, stream>>>(g); }
    { GemmArgs g{}; g.M=1024; g.N=1024; g.K=1024; g.ldK=1024;
      g.A[0]=arb; g.B[0]=WrchT; g.C[0]=out; g.epi[0]=EPI_SIGMUL4; g.obf[0]=0;
      g.p1[0]=kpart; g.p2[0]=x2buf;
      mgemm_k<<<dim3(16,16,1), 256, 0, stream>>>(g); }
}

// Round 14
// 184.742 us; speedup vs baseline: 1.0307x; 1.0307x over previous
//
#include <hip/hip_runtime.h>
#include <math.h>

// RWKV block forward, MI355X — round 14: revert to best-measured round-11
// configuration (185.0 us). 18 dispatches.
#define T_  512
#define E_  1024
#define BTE 1048576

enum { EPI_NONE=0, EPI_TANH=1, EPI_SILU=2, EPI_RELU2=3, EPI_WLOG=4, EPI_ADDRES=5,
       EPI_SIGMUL4=6 };

typedef __attribute__((ext_vector_type(8))) short bf16x8;
typedef __attribute__((ext_vector_type(4))) float f32x4;

__device__ __forceinline__ unsigned short f2bf(float f) {
    union { float f; unsigned u; } v; v.f = f;
    unsigned r = v.u + 0x7fffu + ((v.u >> 16) & 1u);
    return (unsigned short)(r >> 16);
}
__device__ __forceinline__ float bf2f(unsigned short h) {
    union { unsigned u; float f; } v; v.u = ((unsigned)h) << 16;
    return v.f;
}

// ---------------- fused LN1 + time-shift mix: xn (f32) + xmix (bf16) ----------------
__global__ __launch_bounds__(256) void ln1mix_k(const float* __restrict__ x,
        const float* __restrict__ sc, const float* __restrict__ bi,
        const float* __restrict__ maa,
        float* __restrict__ xn, unsigned short* __restrict__ xmix)
{
    const int row = blockIdx.x;
    const int t = row & 511;
    const int tid = threadIdx.x;
    const float* xr = x + (size_t)row * E_;
    float4 v = *reinterpret_cast<const float4*>(xr + tid*4);
    float4 vp = make_float4(0.f, 0.f, 0.f, 0.f);
    if (t) vp = *reinterpret_cast<const float4*>(xr - E_ + tid*4);
    float s   = v.x + v.y + v.z + v.w;
    float ss  = v.x*v.x + v.y*v.y + v.z*v.z + v.w*v.w;
    float sp  = vp.x + vp.y + vp.z + vp.w;
    float ssp = vp.x*vp.x + vp.y*vp.y + vp.z*vp.z + vp.w*vp.w;
    #pragma unroll
    for (int off = 32; off > 0; off >>= 1) {
        s   += __shfl_down(s, off);
        ss  += __shfl_down(ss, off);
        sp  += __shfl_down(sp, off);
        ssp += __shfl_down(ssp, off);
    }
    __shared__ float p0[4], p1[4], p2[4], p3[4];
    __shared__ float st[4];
    if ((tid & 63) == 0) { p0[tid>>6]=s; p1[tid>>6]=ss; p2[tid>>6]=sp; p3[tid>>6]=ssp; }
    __syncthreads();
    if (tid == 0) {
        float S  = p0[0]+p0[1]+p0[2]+p0[3];
        float SS = p1[0]+p1[1]+p1[2]+p1[3];
        float Sp = p2[0]+p2[1]+p2[2]+p2[3];
        float SSp= p3[0]+p3[1]+p3[2]+p3[3];
        float mu  = S * (1.f/E_);
        float var = SS * (1.f/E_) - mu*mu;
        float mup = Sp * (1.f/E_);
        float varp= SSp * (1.f/E_) - mup*mup;
        st[0] = mu; st[1] = rsqrtf(var + 1e-5f);
        st[2] = mup; st[3] = rsqrtf(varp + 1e-5f);
    }
    __syncthreads();
    const float mu = st[0], rstd = st[1], mup = st[2], rstdp = st[3];
    float4 s4 = *reinterpret_cast<const float4*>(sc + tid*4);
    float4 b4 = *reinterpret_cast<const float4*>(bi + tid*4);
    float xnv[4], prv[4];
    xnv[0]=(v.x-mu)*rstd*s4.x+b4.x; xnv[1]=(v.y-mu)*rstd*s4.y+b4.y;
    xnv[2]=(v.z-mu)*rstd*s4.z+b4.z; xnv[3]=(v.w-mu)*rstd*s4.w+b4.w;
    prv[0]=t?(vp.x-mup)*rstdp*s4.x+b4.x:0.f; prv[1]=t?(vp.y-mup)*rstdp*s4.y+b4.y:0.f;
    prv[2]=t?(vp.z-mup)*rstdp*s4.z+b4.z:0.f; prv[3]=t?(vp.w-mup)*rstdp*s4.w+b4.w:0.f;
    float4 o; o.x=xnv[0]; o.y=xnv[1]; o.z=xnv[2]; o.w=xnv[3];
    *reinterpret_cast<float4*>(xn + (size_t)row*E_ + tid*4) = o;
    #pragma unroll
    for (int j = 0; j < 4; ++j) {
        int e = tid*4 + j;
        xmix[(size_t)row*E_ + e] = f2bf(xnv[j] + (prv[j]-xnv[j])*maa[e]);
    }
}

// ---------------- fused Wo-splitK reduce + residual + LN2 + channel-shift ----------------
// x2 = p0 + p1 + x (written for the final epilogue's residual), then LN2+shift.
__global__ __launch_bounds__(256) void ln2mix_k(const float* __restrict__ pa,
        const float* __restrict__ pb, const float* __restrict__ xres,
        const float* __restrict__ sc, const float* __restrict__ bi,
        const float* __restrict__ maaK, const float* __restrict__ maaR,
        float* __restrict__ x2out,
        unsigned short* __restrict__ ak, unsigned short* __restrict__ ar)
{
    const int row = blockIdx.x;
    const int t = row & 511;
    const int tid = threadIdx.x;
    const size_t off = (size_t)row*E_ + tid*4;
    float4 a0 = *reinterpret_cast<const float4*>(pa + off);
    float4 a1 = *reinterpret_cast<const float4*>(pb + off);
    float4 xv = *reinterpret_cast<const float4*>(xres + off);
    float4 v;
    v.x = a0.x + a1.x + xv.x; v.y = a0.y + a1.y + xv.y;
    v.z = a0.z + a1.z + xv.z; v.w = a0.w + a1.w + xv.w;
    float4 vp = make_float4(0.f, 0.f, 0.f, 0.f);
    if (t) {
        float4 b0 = *reinterpret_cast<const float4*>(pa + off - E_);
        float4 b1 = *reinterpret_cast<const float4*>(pb + off - E_);
        float4 bx = *reinterpret_cast<const float4*>(xres + off - E_);
        vp.x = b0.x + b1.x + bx.x; vp.y = b0.y + b1.y + bx.y;
        vp.z = b0.z + b1.z + bx.z; vp.w = b0.w + b1.w + bx.w;
    }
    *reinterpret_cast<float4*>(x2out + off) = v;
    float s   = v.x + v.y + v.z + v.w;
    float ss  = v.x*v.x + v.y*v.y + v.z*v.z + v.w*v.w;
    float sp  = vp.x + vp.y + vp.z + vp.w;
    float ssp = vp.x*vp.x + vp.y*vp.y + vp.z*vp.z + vp.w*vp.w;
    #pragma unroll
    for (int off2 = 32; off2 > 0; off2 >>= 1) {
        s   += __shfl_down(s, off2);
        ss  += __shfl_down(ss, off2);
        sp  += __shfl_down(sp, off2);
        ssp += __shfl_down(ssp, off2);
    }
    __shared__ float q0[4], q1[4], q2[4], q3[4];
    __shared__ float st[4];
    if ((tid & 63) == 0) { q0[tid>>6]=s; q1[tid>>6]=ss; q2[tid>>6]=sp; q3[tid>>6]=ssp; }
    __syncthreads();
    if (tid == 0) {
        float S  = q0[0]+q0[1]+q0[2]+q0[3];
        float SS = q1[0]+q1[1]+q1[2]+q1[3];
        float Sp = q2[0]+q2[1]+q2[2]+q2[3];
        float SSp= q3[0]+q3[1]+q3[2]+q3[3];
        float mu  = S * (1.f/E_);
        float var = SS * (1.f/E_) - mu*mu;
        float mup = Sp * (1.f/E_);
        float varp= SSp * (1.f/E_) - mup*mup;
        st[0] = mu; st[1] = rsqrtf(var + 1e-5f);
        st[2] = mup; st[3] = rsqrtf(varp + 1e-5f);
    }
    __syncthreads();
    const float mu = st[0], rstd = st[1], mup = st[2], rstdp = st[3];
    float4 s4 = *reinterpret_cast<const float4*>(sc + tid*4);
    float4 b4 = *reinterpret_cast<const float4*>(bi + tid*4);
    float xnv[4], prv[4];
    xnv[0]=(v.x-mu)*rstd*s4.x+b4.x; xnv[1]=(v.y-mu)*rstd*s4.y+b4.y;
    xnv[2]=(v.z-mu)*rstd*s4.z+b4.z; xnv[3]=(v.w-mu)*rstd*s4.w+b4.w;
    prv[0]=t?(vp.x-mup)*rstdp*s4.x+b4.x:0.f; prv[1]=t?(vp.y-mup)*rstdp*s4.y+b4.y:0.f;
    prv[2]=t?(vp.z-mup)*rstdp*s4.z+b4.z:0.f; prv[3]=t?(vp.w-mup)*rstdp*s4.w+b4.w:0.f;
    #pragma unroll
    for (int j = 0; j < 4; ++j) {
        int e = tid*4 + j;
        float sxv = prv[j] - xnv[j];
        ak[(size_t)row*E_ + e] = f2bf(xnv[j] + sxv*maaK[e]);
        ar[(size_t)row*E_ + e] = f2bf(xnv[j] + sxv*maaR[e]);
    }
}

// ---------------- t5 split-K reduce + tanh + repack ----------------
__global__ __launch_bounds__(256) void t5red_k(const float* __restrict__ tp,
        unsigned short* __restrict__ t5p)
{
    int idx = blockIdx.x*256 + threadIdx.x;          // < 5*1024*64
    int c = idx & 63, bt = (idx >> 6) & 1023, g = idx >> 16;
    unsigned short o = 0;
    if (c < 32) {
        float s = 0.f;
        size_t off = (size_t)bt*160 + g*32 + c;
        #pragma unroll
        for (int z = 0; z < 8; ++z) s += tp[(size_t)z*163840 + off];
        o = f2bf(tanhf(s));
    }
    t5p[idx] = o;
}

// ---------------- dw1 split-K reduce + tanh -> bf16 ----------------
__global__ __launch_bounds__(256) void dw1red_k(const float* __restrict__ dp,
        unsigned short* __restrict__ h)
{
    int idx = blockIdx.x*256 + threadIdx.x;          // < 65536
    float s = 0.f;
    #pragma unroll
    for (int z = 0; z < 8; ++z) s += dp[(size_t)z*65536 + idx];
    h[idx] = f2bf(tanhf(s));
}

// ---------------- mix5 apply (reshape quirk) ----------------
__global__ __launch_bounds__(256) void mix5_apply_k(const float* __restrict__ xn,
        const unsigned short* __restrict__ mb,
        const float* __restrict__ maaW, const float* __restrict__ maaK,
        const float* __restrict__ maaV, const float* __restrict__ maaR,
        const float* __restrict__ maaG,
        unsigned short* __restrict__ xw, unsigned short* __restrict__ xk,
        unsigned short* __restrict__ xv, unsigned short* __restrict__ xr,
        unsigned short* __restrict__ xg)
{
    int idx = blockIdx.x*256 + threadIdx.x;
    int e = idx & 1023;
    int bt = idx >> 10;
    int b = bt >> 9, t = bt & 511;
    float xnv = xn[idx];
    float prev = t ? xn[idx - E_] : 0.f;
    float sxv = prev - xnv;
    float m[5];
    #pragma unroll
    for (int o = 0; o < 5; ++o) {
        int L = o*2 + b;
        int bs = L / 5, gs = L - bs*5;
        m[o] = bf2f(mb[(size_t)gs*1048576 + (size_t)(bs*T_ + t)*E_ + e]);
    }
    xw[idx] = f2bf(xnv + sxv*(maaW[e] + m[0]));
    xk[idx] = f2bf(xnv + sxv*(maaK[e] + m[1]));
    xv[idx] = f2bf(xnv + sxv*(maaV[e] + m[2]));
    xr[idx] = f2bf(xnv + sxv*(maaR[e] + m[3]));
    xg[idx] = f2bf(xnv + sxv*(maaG[e] + m[4]));
}

// ---------------- ALL weight convert+transpose in ONE launch ----------------
struct WTA {
    const float* src[16];
    unsigned short* dst[16];
    int K[16], N[16], Npad[16], Kpad[16], tx[16];
    int cum[17];
};
__global__ __launch_bounds__(256) void wtransall_k(WTA a)
{
    int bid = blockIdx.x;
    int s = 0;
    while (bid >= a.cum[s+1]) ++s;
    const int local = bid - a.cum[s];
    const int bx = local % a.tx[s];
    const int by = local / a.tx[s];
    const float* S = a.src[s];
    unsigned short* D = a.dst[s];
    const int K = a.K[s], N = a.N[s], Npad = a.Npad[s], Kpad = a.Kpad[s];
    __shared__ float t[64][65];
    const int tid = threadIdx.x;
    const int k0 = by*64, n0 = bx*64;
    #pragma unroll
    for (int i = 0; i < 16; ++i) {
        int r = i*4 + (tid >> 6), c = tid & 63;
        int gk = k0 + r, gn = n0 + c;
        t[r][c] = (gk < K && gn < N) ? S[(size_t)gk*N + gn] : 0.f;
    }
    __syncthreads();
    #pragma unroll
    for (int i = 0; i < 16; ++i) {
        int r = i*4 + (tid >> 6), c = tid & 63;
        int gn = n0 + r, gk = k0 + c;
        if (gn < Npad && gk < Kpad)
            D[(size_t)gn*Kpad + gk] = f2bf(t[c][r]);
    }
}

// ---------------- 64x64-tile bf16 MFMA GEMM (split-K + XCD swizzle) ----------------
struct GemmArgs {
    const unsigned short* A[8];
    const unsigned short* B[8];
    void* C[8];
    const float* p1[8];
    const float* p2[8];
    int epi[8];
    int obf[8];
    int k0[8];
    int M, N, K, ldK;
};
__global__ __launch_bounds__(256) void mgemm_k(GemmArgs g)
{
    const int bz = blockIdx.z;
    const unsigned short* Ag = g.A[bz];
    const unsigned short* BT = g.B[bz];
    const int N = g.N, K = g.K;
    const int gx = gridDim.x, gy = gridDim.y;
    const int lin = blockIdx.x + gx*blockIdx.y;
    const int q = (gx*gy) >> 3;
    const int tile = (lin & 7)*q + (lin >> 3);
    const int bx = tile / gy;
    const int by = tile - bx*gy;
    const int m0 = by * 64, n0 = bx * 64;
    const int tid = threadIdx.x;
    const int lane = tid & 63, w = tid >> 6;

    __shared__ __align__(16) unsigned short As[2][4096];
    __shared__ __align__(16) unsigned short Bs[2][4096];

    const size_t rowBytes = (size_t)g.ldK * 2;
    int sI[4], sIsB[4]; size_t sOff[4];
    #pragma unroll
    for (int ii = 0; ii < 4; ++ii) {
        int t = w*4 + ii;
        int isB = t >> 3;
        int i = t & 7;
        int r = i*8 + (lane >> 3);
        int gb = ((lane & 7) * 16) ^ ((r & 7) << 4);
        sI[ii] = i; sIsB[ii] = isB;
        int srow = (isB ? n0 : m0) + r;
        sOff[ii] = (size_t)srow * rowBytes + gb;
    }
    auto stage = [&](int buf, size_t kbyte) {
        #pragma unroll
        for (int ii = 0; ii < 4; ++ii) {
            const char* src = (const char*)(sIsB[ii] ? BT : Ag) + sOff[ii] + kbyte;
            unsigned short* dst = (sIsB[ii] ? Bs[buf] : As[buf]) + sI[ii]*512;
            auto g1 = (const __attribute__((address_space(1))) unsigned int*)(src);
            auto l3 = (__attribute__((address_space(3))) unsigned int*)(uintptr_t)(dst);
            __builtin_amdgcn_global_load_lds(g1, l3, 16, 0, 0);
        }
    };

    const int wm = (w >> 1) * 32, wn = (w & 1) * 32;
    const int lr = lane & 15, lk = lane >> 4;
    int aoff[2][2], boff[2][2];
    #pragma unroll
    for (int mi = 0; mi < 2; ++mi)
        #pragma unroll
        for (int kw = 0; kw < 2; ++kw) {
            int ar = wm + mi*16 + lr;
            aoff[mi][kw] = ar*128 + ((kw*64 + lk*16) ^ ((ar & 7) << 4));
            int br = wn + mi*16 + lr;
            boff[mi][kw] = br*128 + ((kw*64 + lk*16) ^ ((br & 7) << 4));
        }

    f32x4 acc[2][2] = {};
    const size_t kbase = (size_t)g.k0[bz] * 2;
    stage(0, kbase);
    const int nk = K >> 6;
    int cur = 0;
    for (int kt = 0; kt < nk; ++kt) {
        __syncthreads();
        if (kt + 1 < nk) stage(cur ^ 1, kbase + (size_t)(kt + 1) * 128);
        const char* Ab = (const char*)As[cur];
        const char* Bb = (const char*)Bs[cur];
        bf16x8 af[2][2], bfv[2][2];
        #pragma unroll
        for (int mi = 0; mi < 2; ++mi)
            #pragma unroll
            for (int kw = 0; kw < 2; ++kw) {
                af[mi][kw]  = *(const bf16x8*)(Ab + aoff[mi][kw]);
                bfv[mi][kw] = *(const bf16x8*)(Bb + boff[mi][kw]);
            }
        #pragma unroll
        for (int kw = 0; kw < 2; ++kw)
            #pragma unroll
            for (int mi = 0; mi < 2; ++mi)
                #pragma unroll
                for (int ni = 0; ni < 2; ++ni)
                    acc[mi][ni] = __builtin_amdgcn_mfma_f32_16x16x32_bf16(
                        af[mi][kw], bfv[ni][kw], acc[mi][ni], 0, 0, 0);
        cur ^= 1;
    }

    const int epi = g.epi[bz], obf = g.obf[bz];
    const float* p1 = g.p1[bz];
    const float* p2 = g.p2[bz];
    float* Cf = (float*)g.C[bz];
    unsigned short* Ch = (unsigned short*)g.C[bz];
    #pragma unroll
    for (int mi = 0; mi < 2; ++mi) {
        #pragma unroll
        for (int ni = 0; ni < 2; ++ni) {
            #pragma unroll
            for (int j = 0; j < 4; ++j) {
                int gm = m0 + wm + mi*16 + lk*4 + j;
                int gn = n0 + wn + ni*16 + lr;
                if (gn >= N) continue;
                size_t idx = (size_t)gm * N + gn;
                float a = acc[mi][ni][j];
                float o = a;
                if (epi == EPI_TANH)        o = tanhf(a);
                else if (epi == EPI_SILU)   o = a / (1.f + expf(-a));
                else if (epi == EPI_RELU2)  { float r = fmaxf(a, 0.f); o = r*r; }
                else if (epi == EPI_WLOG) {
                    float z = -(p1[gn] + a);
                    float sp = (z > 15.f) ? z : log1pf(expf(z));
                    o = logf(fminf(fmaxf(sp, 1e-6f), 1.f));
                }
                else if (epi == EPI_ADDRES) o = a + p1[idx];
                else if (epi == EPI_SIGMUL4) {
                    float kvs = p1[idx] + p1[idx + BTE] + p1[idx + 2*BTE] + p1[idx + 3*BTE];
                    o = p2[idx] + kvs / (1.f + expf(-a));
                }
                if (obf) Ch[idx] = f2bf(o); else Cf[idx] = o;
            }
        }
    }
}

// ---------------- chunkwise pass 1: 1024 threads, early r/k/v prefetch ----------------
#define SWZI(r, c)  (((r) << 6) + ((c) ^ (((r) & 7) << 3)))
#define FIDX(r, kw) (((r) << 6) + ((((kw)*32) + fk*8) ^ (((r) & 7) << 3)))
__global__ __launch_bounds__(1024, 4) void chunk1_k(
    const unsigned short* __restrict__ rb, const unsigned short* __restrict__ kb,
    const unsigned short* __restrict__ vb,
    const unsigned short* __restrict__ hdecb, const unsigned short* __restrict__ dw2T,
    const float* __restrict__ tdecay, const float* __restrict__ faaaa,
    float* __restrict__ ypart, unsigned short* __restrict__ Ug,
    unsigned short* __restrict__ RDimg, unsigned short* __restrict__ BFb,
    float* __restrict__ B63g)
{
    const int blk = blockIdx.x;           // bh*8 + nc
    const int bh = blk >> 3, nc = blk & 7;
    const int b = bh >> 4, h = bh & 15;
    const int tid = threadIdx.x;
    const int l = tid & 63, w = tid >> 6;          // w in [0,16)
    const int jl = l, q = w;
    const int fr = l & 15, fk = l >> 4;
    const int wm = (w >> 2) * 16, wn = (w & 3) * 16;
    const int t0 = nc * 64;

    __shared__ float sQS[16][64];
    __shared__ float sUD[64];
    __shared__ __align__(16) unsigned short pool[32768];   // 64 KB
    unsigned short* sRDb  = pool;
    unsigned short* sKAb  = pool + 4096;
    unsigned short* sKA2b = pool + 8192;    // phase C+: BF bf16 (linear [t*64+k])
    unsigned short* sKATb = pool + 12288;
    unsigned short* sVTb  = pool + 16384;
    unsigned short* sVXTb = pool + 20480;
    unsigned short* sQMb  = pool + 24576;   // W0: hdec image
    unsigned short* sPMb  = pool + 28672;   // W0: dw2T image
    float* wlogf = (float*)(pool + 12288);  // 16KB over sKATb+sVTb (dead until A2)

    const float u_reg = faaaa[h*64 + jl];
    const size_t base = (size_t)b*T_*E_ + (size_t)h*64;
    const size_t coff = (size_t)blk * 4096;

    // ---- Prefetch r/k/v into registers NOW (consumed in A2; latency hides
    //      under W0 stage + W1 MFMA + A1 cumsum). Indices depend on nothing.
    unsigned short rh[4], kh[4], vh[4];
    #pragma unroll
    for (int c = 0; c < 4; ++c) {
        const size_t gi = base + (size_t)(t0 + q*4 + c)*E_ + jl;
        rh[c] = rb[gi]; kh[c] = kb[gi]; vh[c] = vb[gi];
    }

    // ---- W0: stage hdec rows (b*512+t0..+63) and dw2T rows (h*64..+63) ----
    {
        const int isB = w >> 3;            // waves 0-7: hdec, 8-15: dw2T
        const int i = w & 7;               // segment 0..7
        const int r = i*8 + (l >> 3);      // 0..63
        const int gb = ((l & 7)*16) ^ ((r & 7) << 4);
        const char* src = isB
            ? ((const char*)dw2T  + (size_t)(h*64 + r)*128 + gb)
            : ((const char*)hdecb + (size_t)(b*T_ + t0 + r)*128 + gb);
        unsigned short* dst = (isB ? sPMb : sQMb) + i*512;
        auto g1 = (const __attribute__((address_space(1))) unsigned int*)(src);
        auto l3 = (__attribute__((address_space(3))) unsigned int*)(uintptr_t)(dst);
        __builtin_amdgcn_global_load_lds(g1, l3, 16, 0, 0);
    }
    __syncthreads();

    // ---- W1: off = hdec @ dw2T^T via MFMA; wlog (f32) -> wlogf ----
    {
        f32x4 accO = {};
        #pragma unroll
        for (int kw = 0; kw < 2; ++kw) {
            bf16x8 aH = *(const bf16x8*)(&sQMb[FIDX(wm + fr, kw)]);
            bf16x8 bD = *(const bf16x8*)(&sPMb[FIDX(wn + fr, kw)]);
            accO = __builtin_amdgcn_mfma_f32_16x16x32_bf16(aH, bD, accO, 0,0,0);
        }
        const float td = tdecay[h*64 + wn + fr];
        #pragma unroll
        for (int reg = 0; reg < 4; ++reg) {
            const int t = wm + fk*4 + reg;
            const int col = wn + fr;
            float z = -(td + accO[reg]);
            float sp = (z > 15.f) ? z : log1pf(expf(z));
            wlogf[t*64 + col] = logf(fminf(fmaxf(sp, 1e-6f), 1.f));
        }
    }
    __syncthreads();

    // ---- A1: per-wave cumsum of wlog (4 rows each, from wlogf) ----
    float loc[4], vreg[4];
    {
        float cum = 0.f;
        #pragma unroll
        for (int c = 0; c < 4; ++c) {
            float wv = wlogf[(q*4 + c)*64 + jl];
            cum += wv; loc[c] = cum;
        }
        sQS[q][jl] = cum;
    }
    __syncthreads();    // also separates wlogf reads from A2's sKATb/sVTb writes
    float pre = 0.f, atot = 0.f;
    #pragma unroll
    for (int qq = 0; qq < 16; ++qq) {
        float v = sQS[qq][jl];
        atot += v;
        if (qq < q) pre += v;
    }

    // A2: prefetched r/k/v -> RD/KA/KA2/KAT/VT + udiag via in-wave shfl reduce
    #pragma unroll
    for (int c = 0; c < 4; ++c) {
        const int t = q*4 + c;
        const float rv = bf2f(rh[c]), kv = bf2f(kh[c]), vv = bf2f(vh[c]);
        vreg[c] = vv;
        const float a = loc[c] + pre;
        const float aprev = (c > 0) ? (loc[c-1] + pre) : pre;   // == 0 for t==0
        sRDb [SWZI(t, jl)] = f2bf(rv * expf(aprev));
        const float ka = kv * expf(atot - a);
        sKAb [SWZI(t, jl)] = f2bf(ka);
        sKA2b[SWZI(t, jl)] = f2bf(kv * expf(-a));
        sKATb[SWZI(jl, t)] = f2bf(ka);
        sVTb [SWZI(jl, t)] = f2bf(vv);
        float p = rv * u_reg * kv;
        #pragma unroll
        for (int off = 32; off > 0; off >>= 1) p += __shfl_down(p, off);
        if (jl == 0) sUD[t] = p;
    }
    __syncthreads();

    // B: Q = RD@KA2^T, P = RD@KA^T   (per wave: one 16x16 tile)
    f32x4 accQ = {}, accP = {};
    #pragma unroll
    for (int kw = 0; kw < 2; ++kw) {
        bf16x8 ar  = *(const bf16x8*)(&sRDb [FIDX(wm + fr, kw)]);
        bf16x8 bka = *(const bf16x8*)(&sKAb [FIDX(wn + fr, kw)]);
        bf16x8 bk2 = *(const bf16x8*)(&sKA2b[FIDX(wn + fr, kw)]);
        accQ = __builtin_amdgcn_mfma_f32_16x16x32_bf16(ar, bk2, accQ, 0,0,0);
        accP = __builtin_amdgcn_mfma_f32_16x16x32_bf16(ar, bka, accP, 0,0,0);
    }
    // masked write QM (tril-1 + udiag), PM (tril-1); own regions, no race
    #pragma unroll
    for (int reg = 0; reg < 4; ++reg) {
        int t = wm + fk*4 + reg;
        int s = wn + fr;
        float qv = (s < t) ? accQ[reg] : ((s == t) ? sUD[t] : 0.f);
        float pv = (s < t) ? accP[reg] : 0.f;
        sQMb[SWZI(t, s)] = f2bf(qv);
        sPMb[SWZI(t, s)] = f2bf(pv);
    }

    // C: Bcum = cumsum_t(A); BF (bf16) -> sKA2b + global; VXT; B63
    float loc2[4];
    {
        float cum2 = 0.f;
        #pragma unroll
        for (int c = 0; c < 4; ++c) {
            cum2 += loc[c] + pre;
            loc2[c] = cum2;
        }
        sQS[q][jl] = cum2;
    }
    __syncthreads();    // also separates B's sKA2b reads from C's BF writes
    {
        float pre2 = 0.f;
        #pragma unroll
        for (int qq = 0; qq < 16; ++qq) if (qq < q) pre2 += sQS[qq][jl];
        #pragma unroll
        for (int c = 0; c < 4; ++c) {
            const int t = q*4 + c;
            const float Bv = loc2[c] + pre2;
            const float Bprev = (c > 0) ? (loc2[c-1] + pre2) : pre2;
            const unsigned short bfh = f2bf(expf(Bprev));
            sKA2b[t*64 + jl] = bfh;
            BFb[coff + t*64 + jl] = bfh;
            sVXTb[SWZI(jl, t)] = f2bf(vreg[c] * expf(-Bv));
            if (t == 63) B63g[(size_t)blk*64 + jl] = expf(Bv);
        }
    }
    __syncthreads();

    // D: Yintra(QM,VT) + Yloc(PM,VXT) + U(KAT,VXT)
    {
        f32x4 accI = {}, accL = {}, accU = {};
        #pragma unroll
        for (int kw = 0; kw < 2; ++kw) {
            bf16x8 aQ = *(const bf16x8*)(&sQMb [FIDX(wm + fr, kw)]);
            bf16x8 aP = *(const bf16x8*)(&sPMb [FIDX(wm + fr, kw)]);
            bf16x8 aK = *(const bf16x8*)(&sKATb[FIDX(wm + fr, kw)]);
            bf16x8 bV = *(const bf16x8*)(&sVTb [FIDX(wn + fr, kw)]);
            bf16x8 bX = *(const bf16x8*)(&sVXTb[FIDX(wn + fr, kw)]);
            accI = __builtin_amdgcn_mfma_f32_16x16x32_bf16(aQ, bV, accI, 0,0,0);
            accL = __builtin_amdgcn_mfma_f32_16x16x32_bf16(aP, bX, accL, 0,0,0);
            accU = __builtin_amdgcn_mfma_f32_16x16x32_bf16(aK, bX, accU, 0,0,0);
        }
        #pragma unroll
        for (int reg = 0; reg < 4; ++reg) {
            int t = wm + fk*4 + reg;   // == j for U
            int k = wn + fr;
            float bfv = bf2f(sKA2b[t*64 + k]);
            ypart[base + (size_t)(t0 + t)*E_ + k] = accI[reg] + bfv*accL[reg];
            Ug[coff + t*64 + k] = f2bf(accU[reg]);
        }
    }
    // dump swizzled RD image (first 512 threads x 16B = 8 KB)
    if (tid < 512)
        ((bf16x8*)(RDimg + coff))[tid] = ((const bf16x8*)sRDb)[tid];
}

// ---------------- chunkwise pass 2: sequential state scan (Ug bf16) ----------------
__global__ __launch_bounds__(256) void chunk2_k(
    const float* __restrict__ st_in, const unsigned short* __restrict__ Ug,
    const float* __restrict__ B63g,
    unsigned short* __restrict__ Simg, float* __restrict__ st_out)
{
    const int bh = blockIdx.x;
    const int tid = threadIdx.x;
    __shared__ float S[4096];
    for (int i = tid; i < 4096; i += 256) S[i] = st_in[(size_t)bh*4096 + i];
    __syncthreads();
    const int k = tid >> 2, j0 = (tid & 3) * 16;
    for (int nc = 0; nc < 8; ++nc) {
        const size_t coff = ((size_t)bh*8 + nc) * 4096;
        #pragma unroll
        for (int hf = 0; hf < 2; ++hf) {
            bf16x8 tmp;
            #pragma unroll
            for (int e = 0; e < 8; ++e) tmp[e] = (short)f2bf(S[(j0 + hf*8 + e)*64 + k]);
            *(bf16x8*)(&Simg[coff + SWZI(k, j0 + hf*8)]) = tmp;
        }
        __syncthreads();
        for (int i = tid; i < 4096; i += 256) {
            int kk = i & 63;
            S[i] = B63g[((size_t)bh*8 + nc)*64 + kk] * (S[i] + bf2f(Ug[coff + i]));
        }
        __syncthreads();
    }
    for (int i = tid; i < 4096; i += 256) st_out[(size_t)bh*4096 + i] = S[i];
}

// ---------------- chunkwise pass 3: y += BF*(RD@S_prev) + GN partials ----------------
__global__ __launch_bounds__(256) void chunk3_k(
    const unsigned short* __restrict__ RDimg, const unsigned short* __restrict__ Simg,
    const unsigned short* __restrict__ BFb, float* __restrict__ yb,
    float* __restrict__ part)
{
    const int blk = blockIdx.x;
    const int bh = blk >> 3, nc = blk & 7;
    const int b = bh >> 4, h = bh & 15;
    const int tid = threadIdx.x;
    const int l = tid & 63, w = tid >> 6;
    const int fr = l & 15, fk = l >> 4;
    const int wm = (w >> 1) * 32, wn = (w & 1) * 32;
    const int t0 = nc * 64;
    __shared__ __align__(16) unsigned short sRDb[4096];
    __shared__ __align__(16) unsigned short sSTb[4096];
    const size_t coff = (size_t)blk * 4096;

    #pragma unroll
    for (int ii = 0; ii < 2; ++ii) {
        int seg = (w*2 + ii) * 512;
        {
            auto g1 = (const __attribute__((address_space(1))) unsigned int*)(RDimg + coff + seg + (l << 3));
            auto l3 = (__attribute__((address_space(3))) unsigned int*)(uintptr_t)(sRDb + seg);
            __builtin_amdgcn_global_load_lds(g1, l3, 16, 0, 0);
        }
        {
            auto g1 = (const __attribute__((address_space(1))) unsigned int*)(Simg + coff + seg + (l << 3));
            auto l3 = (__attribute__((address_space(3))) unsigned int*)(uintptr_t)(sSTb + seg);
            __builtin_amdgcn_global_load_lds(g1, l3, 16, 0, 0);
        }
    }
    __syncthreads();

    f32x4 accS[2][2] = {};
    #pragma unroll
    for (int kw = 0; kw < 2; ++kw) {
        bf16x8 aR[2], bS[2];
        #pragma unroll
        for (int mi = 0; mi < 2; ++mi)
            aR[mi] = *(const bf16x8*)(&sRDb[FIDX(wm + mi*16 + fr, kw)]);
        #pragma unroll
        for (int ni = 0; ni < 2; ++ni)
            bS[ni] = *(const bf16x8*)(&sSTb[FIDX(wn + ni*16 + fr, kw)]);
        #pragma unroll
        for (int mi = 0; mi < 2; ++mi)
            #pragma unroll
            for (int ni = 0; ni < 2; ++ni)
                accS[mi][ni] = __builtin_amdgcn_mfma_f32_16x16x32_bf16(aR[mi], bS[ni], accS[mi][ni], 0,0,0);
    }
    const size_t base = (size_t)b*T_*E_ + (size_t)h*64;
    float s = 0.f, ss = 0.f;
    #pragma unroll
    for (int mi = 0; mi < 2; ++mi)
        #pragma unroll
        for (int ni = 0; ni < 2; ++ni)
            #pragma unroll
            for (int reg = 0; reg < 4; ++reg) {
                int t = wm + mi*16 + fk*4 + reg;
                int k = wn + ni*16 + fr;
                size_t gp = base + (size_t)(t0 + t)*E_ + k;
                float yv = yb[gp] + bf2f(BFb[coff + t*64 + k]) * accS[mi][ni][reg];
                yb[gp] = yv;
                s += yv; ss += yv*yv;
            }
    #pragma unroll
    for (int off = 32; off > 0; off >>= 1) {
        s  += __shfl_down(s, off);
        ss += __shfl_down(ss, off);
    }
    __shared__ float ps[4], pss[4];
    if (l == 0) { ps[w] = s; pss[w] = ss; }
    __syncthreads();
    if (tid == 0) {
        part[blk]       = ps[0]+ps[1]+ps[2]+ps[3];
        part[256 + blk] = pss[0]+pss[1]+pss[2]+pss[3];
    }
}

// ---------------- gn_apply with per-head reduction from chunk3 partials ----------------
__global__ __launch_bounds__(256) void gn_apply_k(const float* __restrict__ y,
        const float* __restrict__ g, const float* __restrict__ part,
        const float* __restrict__ sc, const float* __restrict__ bi,
        unsigned short* __restrict__ z)
{
    __shared__ float smu[16], srs[16];
    const int tid = threadIdx.x;
    if (tid < 16) {
        float s = 0.f, ss = 0.f;
        #pragma unroll
        for (int b = 0; b < 2; ++b)
            #pragma unroll
            for (int ncc = 0; ncc < 8; ++ncc) {
                int ib = (b*16 + tid)*8 + ncc;
                s  += part[ib];
                ss += part[256 + ib];
            }
        float mu  = s * (1.f/65536.f);
        float var = ss * (1.f/65536.f) - mu*mu;
        smu[tid] = mu;
        srs[tid] = rsqrtf(var + 1e-5f);
    }
    __syncthreads();
    int idx = blockIdx.x*256 + tid;
    int d = idx & 1023;
    int h = d >> 6;
    float yn = (y[idx] - smu[h])*srs[h]*sc[d] + bi[d];
    z[idx] = f2bf(yn * g[idx]);
}

// ---------------- launch ----------------
extern "C" void kernel_launch(void* const* d_in, const int* in_sizes, int n_in,
                              void* d_out, int out_size, void* d_ws, size_t ws_size,
                              hipStream_t stream)
{
    const float* x       = (const float*)d_in[0];
    const float* state0  = (const float*)d_in[1];
    const float* maa_x   = (const float*)d_in[2];
    const float* maa_w   = (const float*)d_in[3];
    const float* maa_k   = (const float*)d_in[4];
    const float* maa_v   = (const float*)d_in[5];
    const float* maa_r   = (const float*)d_in[6];
    const float* maa_g   = (const float*)d_in[7];
    const float* tdecay  = (const float*)d_in[8];
    const float* faaaa   = (const float*)d_in[9];
    const float* w1      = (const float*)d_in[10];
    const float* w2      = (const float*)d_in[11];
    const float* dw1     = (const float*)d_in[12];
    const float* dw2     = (const float*)d_in[13];
    const float* Wr      = (const float*)d_in[14];
    const float* Wk      = (const float*)d_in[15];
    const float* Wv      = (const float*)d_in[16];
    const float* Wg      = (const float*)d_in[17];
    const float* Wo      = (const float*)d_in[18];
    const float* lnx_s   = (const float*)d_in[19];
    const float* lnx_b   = (const float*)d_in[20];
    const float* maa_kch = (const float*)d_in[21];
    const float* maa_rch = (const float*)d_in[22];
    const float* Wk_ch   = (const float*)d_in[23];
    const float* Wv_ch   = (const float*)d_in[24];
    const float* Wr_ch   = (const float*)d_in[25];
    const float* ln1_s   = (const float*)d_in[26];
    const float* ln1_b   = (const float*)d_in[27];
    const float* ln2_s   = (const float*)d_in[28];
    const float* ln2_b   = (const float*)d_in[29];

    // ---- workspace layout (f32 block) ----
    float* xn     = (float*)d_ws;               // 1M
    float* t5dead = xn + 1048576;               // 163840
    float* gbuf   = t5dead + 163840;            // 1M (t5/kv partial base)
    float* wlogb  = gbuf + 1048576;             // 1M (mb16 region; Wo p0; kv p1)
    float* ybuf   = wlogb + 1048576;            // 1M (Wo p1; kv p2)
    float* kvb    = ybuf + 1048576;             // 1M (kv p3)
    float* gnpart = kvb + 1048576;              // 1024
    float* gnstat = gnpart + 1024;              // 32 (unused)
    float* b63g   = gnstat + 32;                // 16384
    // ---- ushort block ----
    unsigned short* u = (unsigned short*)(b63g + 16384);
    unsigned short* xmix = u;  u += 1048576;    // reused: dw1 partials, BFb, zbuf
    unsigned short* xw   = u;  u += 1048576;    // reused as ak
    unsigned short* xk   = u;  u += 1048576;    // reused as ar
    unsigned short* xv_  = u;  u += 1048576;    // reused: Ug (bf16) / kk[0:1M]
    unsigned short* xr   = u;  u += 1048576;    // kk[1M:2M]
    unsigned short* xg   = u;  u += 1048576;    // reused: RDimg / kk[2M:3M]
    unsigned short* xtr  = u;  u += 1048576;    // reused: Simg  / kk[3M:4M]
    unsigned short* rb   = u;  u += 1048576;
    unsigned short* kb   = u;  u += 1048576;
    unsigned short* vb   = u;  u += 1048576;
    unsigned short* hdecb= u;  u += 65536;
    unsigned short* WrT  = u;  u += 1048576;
    unsigned short* WkT  = u;  u += 1048576;
    unsigned short* WvT  = u;  u += 1048576;
    unsigned short* WgT  = u;  u += 1048576;
    unsigned short* WoT  = u;  u += 1048576;
    unsigned short* WrchT= u;  u += 1048576;
    unsigned short* WkchT= u;  u += 4194304;    // 4096 x 1024
    unsigned short* WvchT= u;  u += 4194304;    // 1024 x 4096
    unsigned short* w1T  = u;  u += 196608;     // 192 x 1024
    unsigned short* dw1T = u;  u += 65536;      // 64 x 1024
    unsigned short* dw2T = u;  u += 65536;      // 1024 x 64
    unsigned short* W2T5 = u;  u += 327680;     // 5 x 1024 x 64
    unsigned short* t5p  = u;  u += 327680;     // 5 x 1024 x 64
    // aliases
    unsigned short* zbuf  = xmix;
    unsigned short* akb   = xw;
    unsigned short* arb   = xk;
    unsigned short* kkb   = xv_;                // 4M ushorts contiguous
    unsigned short* mb16  = (unsigned short*)wlogb;
    unsigned short* Ug    = xv_;                // 1M ushorts (bf16)
    unsigned short* RDimg = xg;
    unsigned short* Simg  = xtr;
    unsigned short* BFb   = xmix;
    float* tpart = gbuf;        // 8 x 1024x160 f32
    float* dpart = (float*)xmix;// 8 x 1024x64 f32 = 2 MB
    float* kpart = gbuf;        // kv split-K partials: gbuf..kvb contiguous 4xBTE
    float* wop0  = wlogb;       // Wo split-K partials (dead mb16 / ybuf regions)
    float* wop1  = ybuf;

    float* out   = (float*)d_out;
    float* x2buf = out;
    float* stout = out + (size_t)BTE;

    // ---- ALL weight convert+transpose in one launch ----
    {
        WTA a{};
        const float* srcs[16] = {Wr, Wk, Wv, Wg, Wo, Wr_ch, Wk_ch, Wv_ch, w1, dw1, dw2,
                                 w2, w2+32768, w2+65536, w2+98304, w2+131072};
        unsigned short* dsts[16] = {WrT, WkT, WvT, WgT, WoT, WrchT, WkchT, WvchT,
                                    w1T, dw1T, dw2T,
                                    W2T5, W2T5+65536, W2T5+131072, W2T5+196608, W2T5+262144};
        int Ks[16]    = {1024,1024,1024,1024,1024,1024, 1024, 4096, 1024, 1024,   64, 32,32,32,32,32};
        int Ns[16]    = {1024,1024,1024,1024,1024,1024, 4096, 1024,  160,   64, 1024, 1024,1024,1024,1024,1024};
        int Npads[16] = {1024,1024,1024,1024,1024,1024, 4096, 1024,  192,   64, 1024, 1024,1024,1024,1024,1024};
        int Kpads[16] = {1024,1024,1024,1024,1024,1024, 1024, 4096, 1024, 1024,   64, 64,64,64,64,64};
        int cum = 0;
        for (int i = 0; i < 16; ++i) {
            a.src[i] = srcs[i]; a.dst[i] = dsts[i];
            a.K[i] = Ks[i]; a.N[i] = Ns[i]; a.Npad[i] = Npads[i]; a.Kpad[i] = Kpads[i];
            int txc = (Ns[i] + 63) / 64;
            int tyc = (Ks[i] + 63) / 64;
            a.tx[i] = txc;
            a.cum[i] = cum;
            cum += txc * tyc;
        }
        a.cum[16] = cum;
        wtransall_k<<<cum, 256, 0, stream>>>(a);
    }

    // ---- time mixing ----
    ln1mix_k<<<1024, 256, 0, stream>>>(x, ln1_s, ln1_b, maa_x, xn, xmix);
    // t5 GEMM: split-K x8, single launch
    { GemmArgs g{}; g.M=1024; g.N=160; g.K=128; g.ldK=1024;
      for (int z = 0; z < 8; ++z) {
          g.A[z]=xmix; g.B[z]=w1T; g.C[z]=tpart + (size_t)z*163840;
          g.epi[z]=EPI_NONE; g.obf[z]=0; g.k0[z]=z*128;
      }
      mgemm_k<<<dim3(3,16,8), 256, 0, stream>>>(g); }
    t5red_k<<<1280, 256, 0, stream>>>(tpart, t5p);
    { GemmArgs g{}; g.M=1024; g.N=1024; g.K=64; g.ldK=64;
      for (int z = 0; z < 5; ++z) {
          g.A[z]=t5p + (size_t)z*65536; g.B[z]=W2T5 + (size_t)z*65536;
          g.C[z]=mb16 + (size_t)z*1048576; g.epi[z]=EPI_NONE; g.obf[z]=1;
      }
      mgemm_k<<<dim3(16,16,5), 256, 0, stream>>>(g); }
    mix5_apply_k<<<4096, 256, 0, stream>>>(xn, mb16, maa_w, maa_k, maa_v, maa_r, maa_g,
                                           xw, xk, xv_, xr, xg);
    { GemmArgs g{}; g.M=1024; g.N=1024; g.K=1024; g.ldK=1024;
      g.A[0]=xr;  g.B[0]=WrT; g.C[0]=rb;   g.epi[0]=EPI_NONE; g.obf[0]=1;
      g.A[1]=xk;  g.B[1]=WkT; g.C[1]=kb;   g.epi[1]=EPI_NONE; g.obf[1]=1;
      g.A[2]=xv_; g.B[2]=WvT; g.C[2]=vb;   g.epi[2]=EPI_NONE; g.obf[2]=1;
      g.A[3]=xg;  g.B[3]=WgT; g.C[3]=gbuf; g.epi[3]=EPI_SILU; g.obf[3]=0;
      mgemm_k<<<dim3(16,16,4), 256, 0, stream>>>(g); }
    // dw1 GEMM: split-K x8, single launch
    { GemmArgs g{}; g.M=1024; g.N=64; g.K=128; g.ldK=1024;
      for (int z = 0; z < 8; ++z) {
          g.A[z]=xw; g.B[z]=dw1T; g.C[z]=dpart + (size_t)z*65536;
          g.epi[z]=EPI_NONE; g.obf[z]=0; g.k0[z]=z*128;
      }
      mgemm_k<<<dim3(1,16,8), 256, 0, stream>>>(g); }
    dw1red_k<<<256, 256, 0, stream>>>(dpart, hdecb);

    // chunkwise: pass1 (prefetch + 16 waves) -> tiny scan -> pass2 (+GN partials)
    chunk1_k<<<256, 1024, 0, stream>>>(rb, kb, vb, hdecb, dw2T, tdecay, faaaa,
                                       ybuf, Ug, RDimg, BFb, b63g);
    chunk2_k<<<32, 256, 0, stream>>>(state0, Ug, b63g, Simg, stout);
    chunk3_k<<<256, 256, 0, stream>>>(RDimg, Simg, BFb, ybuf, gnpart);

    gn_apply_k<<<4096, 256, 0, stream>>>(ybuf, gbuf, gnpart, lnx_s, lnx_b, zbuf);
    // Wo GEMM: split-K x2 into f32 partials (reduce folded into ln2mix)
    { GemmArgs g{}; g.M=1024; g.N=1024; g.K=512; g.ldK=1024;
      g.A[0]=zbuf; g.B[0]=WoT; g.C[0]=wop0; g.epi[0]=EPI_NONE; g.obf[0]=0; g.k0[0]=0;
      g.A[1]=zbuf; g.B[1]=WoT; g.C[1]=wop1; g.epi[1]=EPI_NONE; g.obf[1]=0; g.k0[1]=512;
      mgemm_k<<<dim3(16,16,2), 256, 0, stream>>>(g); }

    // ---- channel mixing (x2 = wop0 + wop1 + x computed inline) ----
    ln2mix_k<<<1024, 256, 0, stream>>>(wop0, wop1, x, ln2_s, ln2_b,
                                       maa_kch, maa_rch, x2buf, akb, arb);
    { GemmArgs g{}; g.M=1024; g.N=4096; g.K=1024; g.ldK=1024;
      g.A[0]=akb; g.B[0]=WkchT; g.C[0]=kkb; g.epi[0]=EPI_RELU2; g.obf[0]=1;
      mgemm_k<<<dim3(64,16,1), 256, 0, stream>>>(g); }
    { GemmArgs g{}; g.M=1024; g.N=1024; g.K=1024; g.ldK=4096;   // split-K over K=4096
      for (int z = 0; z < 4; ++z) {
          g.A[z]=kkb; g.B[z]=WvchT; g.C[z]=kpart + (size_t)z*BTE;
          g.epi[z]=EPI_NONE; g.obf[z]=0; g.k0[z]=z*1024;
      }
      mgemm_k<<<dim3(16,16,4), 256, 0, stream>>>(g); }
    { GemmArgs g{}; g.M=1024; g.N=1024; g.K=1024; g.ldK=1024;
      g.A[0]=arb; g.B[0]=WrchT; g.C[0]=out; g.epi[0]=EPI_SIGMUL4; g.obf[0]=0;
      g.p1[0]=kpart; g.p2[0]=x2buf;
      mgemm_k<<<dim3(16,16,1), 256, 0, stream>>>(g); }
}